// Round 5
// baseline (483.801 us; speedup 1.0000x reference)
//
#include <hip/hip_runtime.h>
#include <cstdint>
#include <cstddef>

// Model dims
#define Hn 100
#define Tn 25
#define Bn 512
#define FCn 128
#define ROWS 16              // batch rows per block (= MFMA M)
#define NBLK (Bn / ROWS)     // 32 blocks
#define NTHR 512             // 8 waves
#define PITCH 232            // fp16 row pitch: 8*29 -> 16B-aligned rows, odd*4 dwords
#define KPAD 224             // K padded to 7*32

typedef _Float16 v8h __attribute__((ext_vector_type(8)));
typedef float    v4f __attribute__((ext_vector_type(4)));
union U4H8 { uint4 u; v8h h; };

__device__ __forceinline__ float sigm(float x) {
    return __fdividef(1.0f, 1.0f + __expf(-x));
}
__device__ __forceinline__ float tanh_fast(float x) {
    float e = __expf(2.0f * x);
    return __fdividef(e - 1.0f, e + 1.0f);
}

// ---------------------------------------------------------------------------
// Prep: repack k1,k2 (fp32 [200][400], orig col c = g*100+u) into MFMA
// B-fragments, with PERMUTED columns col' = 4u+g (so a unit's 4 gates are
// quad-adjacent in one tile). WB[((l*25+t)*7+kk)*64 + lane], lane = q*16+n:
// uint4 = 8 fp16 = K[kk*32+q*8 .. +8][col'=16t+n], zeros for k>=200.
// ---------------------------------------------------------------------------
__global__ void prep_weights(const float* __restrict__ k1,
                             const float* __restrict__ k2,
                             uint4* __restrict__ WB) {
    int t = blockIdx.x * 256 + threadIdx.x;
    if (t >= 2 * 25 * 7 * 64) return;
    int lane = t & 63;
    int rest = t >> 6;               // (l*25 + tile)*7 + kk
    int kk   = rest % 7;
    int tile = (rest / 7) % 25;
    int l    = rest / (7 * 25);
    int q = lane >> 4, n = lane & 15;
    int colp = tile * 16 + n;        // permuted col'
    int u = colp >> 2, g = colp & 3;
    int c = g * 100 + u;             // original kernel column
    int k0 = kk * 32 + q * 8;
    const float* K = l ? k2 : k1;
    union { unsigned u32; _Float16 h[2]; } d[4];
    #pragma unroll
    for (int j = 0; j < 4; j++) {
        int ka = k0 + 2 * j, kb = ka + 1;
        d[j].h[0] = (_Float16)((ka < 200) ? K[ka * 400 + c] : 0.0f);
        d[j].h[1] = (_Float16)((kb < 200) ? K[kb * 400 + c] : 0.0f);
    }
    uint4 v; v.x = d[0].u32; v.y = d[1].u32; v.z = d[2].u32; v.w = d[3].u32;
    WB[t] = v;
}

// ---------------------------------------------------------------------------
// One layer phase for one wave: A-frags from LDS (xh row-block), B-frags
// streamed from L2, NT tiles of 7 MFMAs each, then in-register quad
// transpose + LSTM cell update; h written to 1-2 LDS destinations.
// Lane decode: q=lane>>4, n=lane&15, v=n>>2, g=n&3.
// acc after K-loop: reg r = z[row 4q+r][col' 16t+n]; lane updates
// (row 4q+g, unit 4t+v) after transpose.
// ---------------------------------------------------------------------------
template<int NT>
__device__ __forceinline__ void layer_phase(
    const uint4* __restrict__ WBl,
    const _Float16* __restrict__ xsrc,
    _Float16* __restrict__ dstA, int offA,
    _Float16* __restrict__ dstB, int offB,     // nullptr -> single dest
    const float* __restrict__ bl,
    float* __restrict__ cst,
    int wv, int lane)
{
    const int q = lane >> 4, n = lane & 15;
    const int g = n & 3, v = n >> 2;

    // B-frags (streamed; coalesced 1KB per instr, L2-resident)
    U4H8 bf[NT][7];
    #pragma unroll
    for (int i = 0; i < NT; i++) {
        int t = 8 * i + wv;
        #pragma unroll
        for (int kk = 0; kk < 7; kk++)
            bf[i][kk].u = WBl[(t * 7 + kk) * 64 + lane];
    }
    // A-frags: lane m=n reads 16B at k = kk*32 + q*8
    U4H8 af[7];
    #pragma unroll
    for (int kk = 0; kk < 7; kk++)
        af[kk].u = *(const uint4*)(xsrc + n * PITCH + kk * 32 + q * 8);

    #pragma unroll
    for (int i = 0; i < NT; i++) {
        v4f acc = { bl[i], bl[i], bl[i], bl[i] };   // bias broadcast over rows
        #pragma unroll
        for (int kk = 0; kk < 7; kk++)
            acc = __builtin_amdgcn_mfma_f32_16x16x32_f16(af[kk].h, bf[i][kk].h, acc, 0, 0, 0);

        // quad 4x4 transpose: w_d = (reg g of lane^d); Z[gamma] = w_{g^gamma}
        float a0 = acc[0], a1 = acc[1], a2 = acc[2], a3 = acc[3];
        bool gb0 = (g & 1) != 0, gb1 = (g & 2) != 0;
        float selA  = gb0 ? a1 : a0;     // a[g&1]
        float selB  = gb0 ? a3 : a2;     // a[2|(g&1)]
        float selA1 = gb0 ? a0 : a1;     // a[(g&1)^1]
        float selB1 = gb0 ? a2 : a3;     // a[2|((g&1)^1)]
        float s0 = gb1 ? selB  : selA;   // a[g]
        float s1 = gb1 ? selB1 : selA1;  // a[g^1]
        float s2 = gb1 ? selA  : selB;   // a[g^2]
        float s3 = gb1 ? selA1 : selB1;  // a[g^3]
        float w0 = s0;
        float w1 = __shfl_xor(s1, 1);
        float w2 = __shfl_xor(s2, 2);
        float w3 = __shfl_xor(s3, 3);
        float p01 = gb0 ? w1 : w0;
        float p10 = gb0 ? w0 : w1;
        float p23 = gb0 ? w3 : w2;
        float p32 = gb0 ? w2 : w3;
        float zi = gb1 ? p23 : p01;      // w_g
        float zj = gb1 ? p32 : p10;      // w_{g^1}
        float zf = gb1 ? p01 : p23;      // w_{g^2}
        float zo = gb1 ? p10 : p32;      // w_{g^3}

        float cn = cst[i] * sigm(zf + 1.0f) + sigm(zi) * tanh_fast(zj);
        cst[i] = cn;
        float h = tanh_fast(cn) * sigm(zo);

        int row = 4 * q + g;
        int uu  = 4 * (8 * i + wv) + v;
        dstA[row * PITCH + offA + uu] = (_Float16)h;
        if (dstB) dstB[row * PITCH + offB + uu] = (_Float16)h;
    }
}

__global__ __launch_bounds__(NTHR, 2) void lstm_main(
    const int*   __restrict__ features,   // [B][T]
    const float* __restrict__ embedding,  // [VOCAB][100]
    const float* __restrict__ b1,         // [400] gate-major
    const float* __restrict__ b2,
    const float* __restrict__ w_fc1,      // [100][128]
    const float* __restrict__ b_fc1,      // [128]
    const float* __restrict__ w_fc2,      // [128][2]
    const float* __restrict__ b_fc2,      // [2]
    const uint4* __restrict__ WB,         // [2][25][7][64] frags
    float*       __restrict__ out)        // [B][2]
{
    __shared__ alignas(16) _Float16 xh1[2][ROWS][PITCH];  // [x | h1 | zero-pad]
    __shared__ alignas(16) _Float16 xh2[2][ROWS][PITCH];  // [h1 | h2 | zero-pad]

    const int tid  = threadIdx.x;
    const int lane = tid & 63;
    const int wv   = tid >> 6;
    const int n    = lane & 15;
    const int g    = n & 3, v = n >> 2;
    const int blk  = blockIdx.x;

    const uint4* WB1 = WB;
    const uint4* WB2 = WB + 25 * 7 * 64;

    // per-tile biases for this lane's column
    const int NTw = (wv == 0) ? 4 : 3;
    float bl1[4] = {0, 0, 0, 0}, bl2[4] = {0, 0, 0, 0};
    for (int i = 0; i < NTw; i++) {
        int t  = 8 * i + wv;
        int cc = g * 100 + (4 * t + v);
        bl1[i] = b1[cc];
        bl2[i] = b2[cc];
    }
    float c1[4] = {0, 0, 0, 0}, c2[4] = {0, 0, 0, 0};

    // zero all xh buffers (incl. the k>=200 pad that MFMA A-frags touch)
    {
        unsigned* p1 = (unsigned*)&xh1[0][0][0];
        unsigned* p2 = (unsigned*)&xh2[0][0][0];
        const int ndw = 2 * ROWS * PITCH / 2;     // dwords per array
        for (int i = tid; i < ndw; i += NTHR) { p1[i] = 0u; p2[i] = 0u; }
    }
    // stage x(0)
    const int rowx = tid / 25, px = tid % 25;     // tid<400: (row, 16B chunk)
    if (tid < 400) {
        int f0 = features[(blk * ROWS + rowx) * Tn + 0];
        float4 e = *(const float4*)(embedding + (size_t)f0 * Hn + 4 * px);
        union { _Float16 h[4]; uint2 u; } pk;
        pk.h[0] = (_Float16)e.x; pk.h[1] = (_Float16)e.y;
        pk.h[2] = (_Float16)e.z; pk.h[3] = (_Float16)e.w;
        *(uint2*)&xh1[0][rowx][4 * px] = pk.u;
    }
    __syncthreads();

    for (int t = 0; t < Tn; t++) {
        const int cur = t & 1, nxt = cur ^ 1;

        // prefetch x(t+1) early (latency hidden by both layer phases)
        float4 xp = {0, 0, 0, 0};
        const bool hasx = (tid < 400) && (t + 1 < Tn);
        if (hasx) {
            int f = features[(blk * ROWS + rowx) * Tn + t + 1];
            xp = *(const float4*)(embedding + (size_t)f * Hn + 4 * px);
        }

        // Layer 1: reads xh1[cur]; h1 -> xh1[nxt][100+] and xh2[cur][0+]
        if (wv == 0)
            layer_phase<4>(WB1, &xh1[cur][0][0], &xh1[nxt][0][0], 100,
                           &xh2[cur][0][0], 0, bl1, c1, wv, lane);
        else
            layer_phase<3>(WB1, &xh1[cur][0][0], &xh1[nxt][0][0], 100,
                           &xh2[cur][0][0], 0, bl1, c1, wv, lane);
        __syncthreads();   // h1 visible before layer-2 reads xh2[cur]

        // Layer 2: reads xh2[cur]; h2 -> xh2[nxt][100+]
        if (wv == 0)
            layer_phase<4>(WB2, &xh2[cur][0][0], &xh2[nxt][0][0], 100,
                           (_Float16*)nullptr, 0, bl2, c2, wv, lane);
        else
            layer_phase<3>(WB2, &xh2[cur][0][0], &xh2[nxt][0][0], 100,
                           (_Float16*)nullptr, 0, bl2, c2, wv, lane);

        // publish x(t+1) into xh1[nxt][0..100)
        if (hasx) {
            union { _Float16 h[4]; uint2 u; } pk;
            pk.h[0] = (_Float16)xp.x; pk.h[1] = (_Float16)xp.y;
            pk.h[2] = (_Float16)xp.z; pk.h[3] = (_Float16)xp.w;
            *(uint2*)&xh1[nxt][rowx][4 * px] = pk.u;
        }
        __syncthreads();   // h2/x visible before next step
    }

    // FC head: final h2 is in xh2[Tn&1][row][100..200)
    // wave wv -> rows {2wv, 2wv+1}; lane j and j+64 columns of FC1
    const _Float16* h2base = &xh2[Tn & 1][0][0];
    #pragma unroll
    for (int rr = 0; rr < 2; rr++) {
        int row = 2 * wv + rr;
        float acc0 = b_fc1[lane];
        float acc1 = b_fc1[lane + 64];
        const _Float16* hp = h2base + row * PITCH + 100;
        for (int u = 0; u < Hn; u++) {
            float hv = (float)hp[u];                       // LDS broadcast
            acc0 = fmaf(hv, w_fc1[u * FCn + lane], acc0);
            acc1 = fmaf(hv, w_fc1[u * FCn + lane + 64], acc1);
        }
        float p0 = acc0 * w_fc2[2 * lane + 0] + acc1 * w_fc2[2 * (lane + 64) + 0];
        float p1 = acc0 * w_fc2[2 * lane + 1] + acc1 * w_fc2[2 * (lane + 64) + 1];
        #pragma unroll
        for (int off = 32; off > 0; off >>= 1) {
            p0 += __shfl_down(p0, off);
            p1 += __shfl_down(p1, off);
        }
        if (lane == 0) {
            out[(blk * ROWS + row) * 2 + 0] = p0 + b_fc2[0];
            out[(blk * ROWS + row) * 2 + 1] = p1 + b_fc2[1];
        }
    }
}

extern "C" void kernel_launch(void* const* d_in, const int* in_sizes, int n_in,
                              void* d_out, int out_size, void* d_ws, size_t ws_size,
                              hipStream_t stream) {
    const int*   features  = (const int*)  d_in[0];
    const float* embedding = (const float*)d_in[1];
    const float* k1        = (const float*)d_in[2];
    const float* b1        = (const float*)d_in[3];
    const float* k2        = (const float*)d_in[4];
    const float* b2        = (const float*)d_in[5];
    const float* w_fc1     = (const float*)d_in[6];
    const float* b_fc1     = (const float*)d_in[7];
    const float* w_fc2     = (const float*)d_in[8];
    const float* b_fc2     = (const float*)d_in[9];

    uint4* WBp = (uint4*)d_ws;    // 2*25*7*64*16 = 358,400 B

    prep_weights<<<(2 * 25 * 7 * 64 + 255) / 256, 256, 0, stream>>>(k1, k2, WBp);
    lstm_main<<<NBLK, NTHR, 0, stream>>>(features, embedding, b1, b2,
                                         w_fc1, b_fc1, w_fc2, b_fc2,
                                         WBp, (float*)d_out);
}

// Round 6
// 355.977 us; speedup vs baseline: 1.3591x; 1.3591x over previous
//
#include <hip/hip_runtime.h>
#include <cstdint>
#include <cstddef>

// Model dims
#define Hn 100
#define Tn 25
#define Bn 512
#define FCn 128
#define ROWS 16              // batch rows per block (= MFMA M)
#define NBLK (Bn / ROWS)     // 32 blocks
#define NTHR 512             // 8 waves
#define PITCH 232            // fp16 row pitch: 16B-aligned rows, odd*4 dwords
#define KPAD 224             // K padded to 7*32

typedef _Float16 v8h __attribute__((ext_vector_type(8)));
typedef float    v4f __attribute__((ext_vector_type(4)));
union U4H8 { uint4 u; v8h h; };

__device__ __forceinline__ float sigm(float x) {
    return __fdividef(1.0f, 1.0f + __expf(-x));
}
__device__ __forceinline__ float tanh_fast(float x) {
    float e = __expf(2.0f * x);
    return __fdividef(e - 1.0f, e + 1.0f);
}

// ---------------------------------------------------------------------------
// Prep: repack k1,k2 (fp32 [200][400], orig col c = g*100+u) into MFMA
// B-fragments, with PERMUTED columns col' = 4u+g (so a unit's 4 gates are
// quad-adjacent in one tile). WB[((l*25+t)*7+kk)*64 + lane], lane = q*16+n:
// uint4 = 8 fp16 = K[kk*32+q*8 .. +8][col'=16t+n], zeros for k>=200.
// ---------------------------------------------------------------------------
__global__ void prep_weights(const float* __restrict__ k1,
                             const float* __restrict__ k2,
                             uint4* __restrict__ WB) {
    int t = blockIdx.x * 256 + threadIdx.x;
    if (t >= 2 * 25 * 7 * 64) return;
    int lane = t & 63;
    int rest = t >> 6;               // (l*25 + tile)*7 + kk
    int kk   = rest % 7;
    int tile = (rest / 7) % 25;
    int l    = rest / (7 * 25);
    int q = lane >> 4, n = lane & 15;
    int colp = tile * 16 + n;        // permuted col'
    int u = colp >> 2, g = colp & 3;
    int c = g * 100 + u;             // original kernel column
    int k0 = kk * 32 + q * 8;
    const float* K = l ? k2 : k1;
    union { unsigned u32; _Float16 h[2]; } d[4];
    #pragma unroll
    for (int j = 0; j < 4; j++) {
        int ka = k0 + 2 * j, kb = ka + 1;
        d[j].h[0] = (_Float16)((ka < 200) ? K[ka * 400 + c] : 0.0f);
        d[j].h[1] = (_Float16)((kb < 200) ? K[kb * 400 + c] : 0.0f);
    }
    uint4 v; v.x = d[0].u32; v.y = d[1].u32; v.z = d[2].u32; v.w = d[3].u32;
    WB[t] = v;
}

// ---------------------------------------------------------------------------
// One layer phase for one wave, 2-deep tile pipeline:
//   load B(tile 0); for i: [prefetch B(i+1)] -> 7 MFMA on B(i) -> cell update.
// #pragma unroll 1 on the tile loop keeps at most 2 tiles of B live (56 VGPR)
// so the allocator cannot recreate round-5's 112-VGPR blob + scratch spill.
// Lane decode: q=lane>>4, n=lane&15, v=n>>2, g=n&3.
// acc after K-loop: reg r = z[row 4q+r][col' 16t+n]; after quad transpose the
// lane updates (row 4q+g, unit 4t+v).
// ---------------------------------------------------------------------------
template<int NT>
__device__ __forceinline__ void layer_phase(
    const uint4* __restrict__ WBl,
    const _Float16* __restrict__ xsrc,
    _Float16* __restrict__ dstA, int offA,
    _Float16* __restrict__ dstB, int offB,     // nullptr -> single dest
    const float* __restrict__ bl,
    float* __restrict__ cst,
    int wv, int lane)
{
    const int q = lane >> 4, n = lane & 15;
    const int g = n & 3, v = n >> 2;

    // tile-0 B-frags issued first; latency overlaps the A-frag ds_reads
    U4H8 bcur[7], bnxt[7];
    #pragma unroll
    for (int kk = 0; kk < 7; kk++)
        bcur[kk].u = WBl[(wv * 7 + kk) * 64 + lane];

    // A-frags: lane n reads 16B at k = kk*32 + q*8
    U4H8 af[7];
    #pragma unroll
    for (int kk = 0; kk < 7; kk++)
        af[kk].u = *(const uint4*)(xsrc + n * PITCH + kk * 32 + q * 8);

    #pragma unroll 1
    for (int i = 0; i < NT; i++) {
        if (i + 1 < NT) {
            int tn = 8 * (i + 1) + wv;
            #pragma unroll
            for (int kk = 0; kk < 7; kk++)
                bnxt[kk].u = WBl[(tn * 7 + kk) * 64 + lane];
        }
        v4f acc = { bl[i], bl[i], bl[i], bl[i] };   // bias broadcast over rows
        #pragma unroll
        for (int kk = 0; kk < 7; kk++)
            acc = __builtin_amdgcn_mfma_f32_16x16x32_f16(af[kk].h, bcur[kk].h, acc, 0, 0, 0);

        // quad 4x4 transpose: Z[gamma] = (reg g of lane^gamma)
        float a0 = acc[0], a1 = acc[1], a2 = acc[2], a3 = acc[3];
        bool gb0 = (g & 1) != 0, gb1 = (g & 2) != 0;
        float selA  = gb0 ? a1 : a0;     // a[g&1]
        float selB  = gb0 ? a3 : a2;     // a[2|(g&1)]
        float selA1 = gb0 ? a0 : a1;     // a[(g&1)^1]
        float selB1 = gb0 ? a2 : a3;     // a[2|((g&1)^1)]
        float s0 = gb1 ? selB  : selA;   // a[g]
        float s1 = gb1 ? selB1 : selA1;  // a[g^1]
        float s2 = gb1 ? selA  : selB;   // a[g^2]
        float s3 = gb1 ? selA1 : selB1;  // a[g^3]
        float w0 = s0;
        float w1 = __shfl_xor(s1, 1);
        float w2 = __shfl_xor(s2, 2);
        float w3 = __shfl_xor(s3, 3);
        float p01 = gb0 ? w1 : w0;
        float p10 = gb0 ? w0 : w1;
        float p23 = gb0 ? w3 : w2;
        float p32 = gb0 ? w2 : w3;
        float zi = gb1 ? p23 : p01;      // w_g
        float zj = gb1 ? p32 : p10;      // w_{g^1}
        float zf = gb1 ? p01 : p23;      // w_{g^2}
        float zo = gb1 ? p10 : p32;      // w_{g^3}

        float cn = cst[i] * sigm(zf + 1.0f) + sigm(zi) * tanh_fast(zj);
        cst[i] = cn;
        float h = tanh_fast(cn) * sigm(zo);

        int row = 4 * q + g;
        int uu  = 4 * (8 * i + wv) + v;
        dstA[row * PITCH + offA + uu] = (_Float16)h;
        if (dstB) dstB[row * PITCH + offB + uu] = (_Float16)h;

        #pragma unroll
        for (int kk = 0; kk < 7; kk++) bcur[kk] = bnxt[kk];
    }
}

__global__ __launch_bounds__(NTHR, 2) void lstm_main(
    const int*   __restrict__ features,   // [B][T]
    const float* __restrict__ embedding,  // [VOCAB][100]
    const float* __restrict__ b1,         // [400] gate-major
    const float* __restrict__ b2,
    const float* __restrict__ w_fc1,      // [100][128]
    const float* __restrict__ b_fc1,      // [128]
    const float* __restrict__ w_fc2,      // [128][2]
    const float* __restrict__ b_fc2,      // [2]
    const uint4* __restrict__ WB,         // [2][25][7][64] frags
    float*       __restrict__ out)        // [B][2]
{
    __shared__ alignas(16) _Float16 xh1[2][ROWS][PITCH];  // [x | h1 | zero-pad]
    __shared__ alignas(16) _Float16 xh2[2][ROWS][PITCH];  // [h1 | h2 | zero-pad]

    const int tid  = threadIdx.x;
    const int lane = tid & 63;
    const int wv   = tid >> 6;
    const int n    = lane & 15;
    const int g    = n & 3, v = n >> 2;
    const int blk  = blockIdx.x;

    const uint4* WB1 = WB;
    const uint4* WB2 = WB + 25 * 7 * 64;

    // per-tile biases for this lane's column
    const int NTw = (wv == 0) ? 4 : 3;
    float bl1[4] = {0, 0, 0, 0}, bl2[4] = {0, 0, 0, 0};
    for (int i = 0; i < NTw; i++) {
        int t  = 8 * i + wv;
        int cc = g * 100 + (4 * t + v);
        bl1[i] = b1[cc];
        bl2[i] = b2[cc];
    }
    float c1[4] = {0, 0, 0, 0}, c2[4] = {0, 0, 0, 0};

    // zero all xh buffers (incl. the k>=200 pad that MFMA A-frags touch)
    {
        unsigned* p1 = (unsigned*)&xh1[0][0][0];
        unsigned* p2 = (unsigned*)&xh2[0][0][0];
        const int ndw = 2 * ROWS * PITCH / 2;     // dwords per array
        for (int i = tid; i < ndw; i += NTHR) { p1[i] = 0u; p2[i] = 0u; }
    }
    // stage x(0)
    const int rowx = tid / 25, px = tid % 25;     // tid<400: (row, 16B chunk)
    if (tid < 400) {
        int f0 = features[(blk * ROWS + rowx) * Tn + 0];
        float4 e = *(const float4*)(embedding + (size_t)f0 * Hn + 4 * px);
        union { _Float16 h[4]; uint2 u; } pk;
        pk.h[0] = (_Float16)e.x; pk.h[1] = (_Float16)e.y;
        pk.h[2] = (_Float16)e.z; pk.h[3] = (_Float16)e.w;
        *(uint2*)&xh1[0][rowx][4 * px] = pk.u;
    }
    __syncthreads();

    for (int t = 0; t < Tn; t++) {
        const int cur = t & 1, nxt = cur ^ 1;

        // prefetch x(t+1) early (latency hidden by both layer phases)
        float4 xp = {0, 0, 0, 0};
        const bool hasx = (tid < 400) && (t + 1 < Tn);
        if (hasx) {
            int f = features[(blk * ROWS + rowx) * Tn + t + 1];
            xp = *(const float4*)(embedding + (size_t)f * Hn + 4 * px);
        }

        // Layer 1: reads xh1[cur]; h1 -> xh1[nxt][100+] and xh2[cur][0+]
        if (wv == 0)
            layer_phase<4>(WB1, &xh1[cur][0][0], &xh1[nxt][0][0], 100,
                           &xh2[cur][0][0], 0, bl1, c1, wv, lane);
        else
            layer_phase<3>(WB1, &xh1[cur][0][0], &xh1[nxt][0][0], 100,
                           &xh2[cur][0][0], 0, bl1, c1, wv, lane);
        __syncthreads();   // h1 visible before layer-2 reads xh2[cur]

        // Layer 2: reads xh2[cur]; h2 -> xh2[nxt][100+]
        if (wv == 0)
            layer_phase<4>(WB2, &xh2[cur][0][0], &xh2[nxt][0][0], 100,
                           (_Float16*)nullptr, 0, bl2, c2, wv, lane);
        else
            layer_phase<3>(WB2, &xh2[cur][0][0], &xh2[nxt][0][0], 100,
                           (_Float16*)nullptr, 0, bl2, c2, wv, lane);

        // publish x(t+1) into xh1[nxt][0..100)
        if (hasx) {
            union { _Float16 h[4]; uint2 u; } pk;
            pk.h[0] = (_Float16)xp.x; pk.h[1] = (_Float16)xp.y;
            pk.h[2] = (_Float16)xp.z; pk.h[3] = (_Float16)xp.w;
            *(uint2*)&xh1[nxt][rowx][4 * px] = pk.u;
        }
        __syncthreads();   // h2/x visible before next step
    }

    // FC head: final h2 is in xh2[Tn&1][row][100..200)
    // wave wv -> rows {2wv, 2wv+1}; lane j and j+64 columns of FC1
    const _Float16* h2base = &xh2[Tn & 1][0][0];
    #pragma unroll
    for (int rr = 0; rr < 2; rr++) {
        int row = 2 * wv + rr;
        float acc0 = b_fc1[lane];
        float acc1 = b_fc1[lane + 64];
        const _Float16* hp = h2base + row * PITCH + 100;
        for (int u = 0; u < Hn; u++) {
            float hv = (float)hp[u];                       // LDS broadcast
            acc0 = fmaf(hv, w_fc1[u * FCn + lane], acc0);
            acc1 = fmaf(hv, w_fc1[u * FCn + lane + 64], acc1);
        }
        float p0 = acc0 * w_fc2[2 * lane + 0] + acc1 * w_fc2[2 * (lane + 64) + 0];
        float p1 = acc0 * w_fc2[2 * lane + 1] + acc1 * w_fc2[2 * (lane + 64) + 1];
        #pragma unroll
        for (int off = 32; off > 0; off >>= 1) {
            p0 += __shfl_down(p0, off);
            p1 += __shfl_down(p1, off);
        }
        if (lane == 0) {
            out[(blk * ROWS + row) * 2 + 0] = p0 + b_fc2[0];
            out[(blk * ROWS + row) * 2 + 1] = p1 + b_fc2[1];
        }
    }
}

extern "C" void kernel_launch(void* const* d_in, const int* in_sizes, int n_in,
                              void* d_out, int out_size, void* d_ws, size_t ws_size,
                              hipStream_t stream) {
    const int*   features  = (const int*)  d_in[0];
    const float* embedding = (const float*)d_in[1];
    const float* k1        = (const float*)d_in[2];
    const float* b1        = (const float*)d_in[3];
    const float* k2        = (const float*)d_in[4];
    const float* b2        = (const float*)d_in[5];
    const float* w_fc1     = (const float*)d_in[6];
    const float* b_fc1     = (const float*)d_in[7];
    const float* w_fc2     = (const float*)d_in[8];
    const float* b_fc2     = (const float*)d_in[9];

    uint4* WBp = (uint4*)d_ws;    // 2*25*7*64*16 = 358,400 B

    prep_weights<<<(2 * 25 * 7 * 64 + 255) / 256, 256, 0, stream>>>(k1, k2, WBp);
    lstm_main<<<NBLK, NTHR, 0, stream>>>(features, embedding, b1, b2,
                                         w_fc1, b_fc1, w_fc2, b_fc2,
                                         WBp, (float*)d_out);
}